// Round 1
// baseline (737.509 us; speedup 1.0000x reference)
//
#include <hip/hip_runtime.h>

#define N_VOX   200000
#define N_PAIRS 100000
#define KK      27
#define INC     64
#define OUTC    64
#define BN_EPS  1e-5f

// ---------------------------------------------------------------------------
// Sparse conv: one wave (64 lanes) per pair. Lane c owns output channel c.
// blockIdx.y = kernel offset k; each wave preloads w[k][:,c] into registers
// and grid-strides over pairs of that k.
// ---------------------------------------------------------------------------
__global__ __launch_bounds__(256) void conv_kernel(
    const float* __restrict__ x, const float* __restrict__ w,
    const int* __restrict__ kin, const int* __restrict__ kout,
    float* __restrict__ y)
{
    const int lane = threadIdx.x & 63;
    const int wid  = threadIdx.x >> 6;           // wave id in block (0..3)
    const int k    = blockIdx.y;

    // Preload this k's weight column for my output channel: wreg[i] = w[k][i][lane]
    float wreg[64];
    const float* wk = w + (size_t)k * (INC * OUTC);
    #pragma unroll
    for (int i = 0; i < 64; ++i) wreg[i] = wk[i * OUTC + lane];

    const int* kin_k  = kin  + (size_t)k * N_PAIRS;
    const int* kout_k = kout + (size_t)k * N_PAIRS;

    const int stride = gridDim.x * 4;            // waves per k
    for (int e = blockIdx.x * 4 + wid; e < N_PAIRS; e += stride) {
        // Pair indices are wave-uniform -> force scalar so x-row loads scalarize
        const int in_idx  = __builtin_amdgcn_readfirstlane(kin_k[e]);
        const int out_idx = __builtin_amdgcn_readfirstlane(kout_k[e]);

        const float* xr = x + (size_t)in_idx * INC;

        float a0 = 0.f, a1 = 0.f, a2 = 0.f, a3 = 0.f;
        #pragma unroll
        for (int i = 0; i < 64; i += 4) {
            a0 = fmaf(xr[i + 0], wreg[i + 0], a0);
            a1 = fmaf(xr[i + 1], wreg[i + 1], a1);
            a2 = fmaf(xr[i + 2], wreg[i + 2], a2);
            a3 = fmaf(xr[i + 3], wreg[i + 3], a3);
        }
        const float acc = (a0 + a1) + (a2 + a3);

        atomicAdd(&y[(size_t)out_idx * OUTC + lane], acc);
    }
}

// ---------------------------------------------------------------------------
// BN stats: per-channel sum and sum-of-squares over all N_VOX rows.
// ---------------------------------------------------------------------------
__global__ __launch_bounds__(256) void bn_reduce(
    const float* __restrict__ y, float* __restrict__ stats)
{
    __shared__ float s_sum[256];
    __shared__ float s_sq[256];

    const int c = threadIdx.x & 63;
    const int row0 = (blockIdx.x * blockDim.x + threadIdx.x) >> 6;
    const int rstride = (gridDim.x * blockDim.x) >> 6;

    float s = 0.f, ss = 0.f;
    for (int r = row0; r < N_VOX; r += rstride) {
        const float v = y[(size_t)r * OUTC + c];
        s += v;
        ss += v * v;
    }
    s_sum[threadIdx.x] = s;
    s_sq[threadIdx.x]  = ss;
    __syncthreads();

    if (threadIdx.x < 64) {
        const float ts  = (s_sum[c] + s_sum[64 + c]) + (s_sum[128 + c] + s_sum[192 + c]);
        const float tss = (s_sq[c]  + s_sq[64 + c])  + (s_sq[128 + c]  + s_sq[192 + c]);
        atomicAdd(&stats[c], ts);
        atomicAdd(&stats[64 + c], tss);
    }
}

// ---------------------------------------------------------------------------
// Fold stats + gamma/beta into per-channel scale/shift.
// ---------------------------------------------------------------------------
__global__ void bn_finalize(
    const float* __restrict__ stats, const float* __restrict__ gamma,
    const float* __restrict__ beta, float* __restrict__ coef)
{
    const int c = threadIdx.x;
    if (c < 64) {
        const float inv_n = 1.0f / (float)N_VOX;
        const float mean  = stats[c] * inv_n;
        const float var   = stats[64 + c] * inv_n - mean * mean;
        const float scale = gamma[c] * rsqrtf(var + BN_EPS);
        coef[c]      = scale;
        coef[64 + c] = beta[c] - mean * scale;
    }
}

// ---------------------------------------------------------------------------
// Apply BN + ReLU in place (float4). Channel phase is invariant per thread
// because the grid stride in floats is a multiple of 64.
// ---------------------------------------------------------------------------
__global__ __launch_bounds__(256) void bn_apply(
    float* __restrict__ y, const float* __restrict__ coef)
{
    const size_t total4 = (size_t)N_VOX * OUTC / 4;
    size_t i = (size_t)blockIdx.x * blockDim.x + threadIdx.x;
    const size_t stride = (size_t)gridDim.x * blockDim.x;   // multiple of 64 f4 = 256 floats

    const int c0 = (int)((i * 4) & 63);
    const float sc0 = coef[c0 + 0], sh0 = coef[64 + c0 + 0];
    const float sc1 = coef[c0 + 1], sh1 = coef[64 + c0 + 1];
    const float sc2 = coef[c0 + 2], sh2 = coef[64 + c0 + 2];
    const float sc3 = coef[c0 + 3], sh3 = coef[64 + c0 + 3];

    float4* y4 = (float4*)y;
    for (; i < total4; i += stride) {
        float4 v = y4[i];
        v.x = fmaxf(0.f, fmaf(v.x, sc0, sh0));
        v.y = fmaxf(0.f, fmaf(v.y, sc1, sh1));
        v.z = fmaxf(0.f, fmaf(v.z, sc2, sh2));
        v.w = fmaxf(0.f, fmaf(v.w, sc3, sh3));
        y4[i] = v;
    }
}

extern "C" void kernel_launch(void* const* d_in, const int* in_sizes, int n_in,
                              void* d_out, int out_size, void* d_ws, size_t ws_size,
                              hipStream_t stream)
{
    const float* x     = (const float*)d_in[0];
    const float* w     = (const float*)d_in[1];
    const float* gamma = (const float*)d_in[2];
    const float* beta  = (const float*)d_in[3];
    const int*   kin   = (const int*)d_in[4];
    const int*   kout  = (const int*)d_in[5];

    float* y     = (float*)d_out;           // [N_VOX, 64] accumulator, then final output
    float* stats = (float*)d_ws;            // [128] sum / sumsq
    float* coef  = stats + 128;             // [128] scale / shift

    hipMemsetAsync(y, 0, (size_t)N_VOX * OUTC * sizeof(float), stream);
    hipMemsetAsync(stats, 0, 128 * sizeof(float), stream);

    conv_kernel<<<dim3(80, KK), 256, 0, stream>>>(x, w, kin, kout, y);
    bn_reduce<<<512, 256, 0, stream>>>(y, stats);
    bn_finalize<<<1, 64, 0, stream>>>(stats, gamma, beta, coef);
    bn_apply<<<2048, 256, 0, stream>>>(y, coef);
}

// Round 2
// 617.306 us; speedup vs baseline: 1.1947x; 1.1947x over previous
//
#include <hip/hip_runtime.h>
#include <cstdint>

#define N_VOX   200000
#define N_PAIRS 100000
#define KK      27
#define INC     64
#define OUTC    64
#define BN_EPS  1e-5f

typedef __attribute__((ext_vector_type(8))) short bf16x8;
typedef __attribute__((ext_vector_type(4))) float f32x4;

__device__ inline uint32_t cvt_pk_bf16(float lo, float hi) {
    uint32_t r;
    asm("v_cvt_pk_bf16_f32 %0, %1, %2" : "=v"(r) : "v"(lo), "v"(hi));
    return r;
}

__device__ inline bf16x8 pack_frag(float a, float b, float c, float d,
                                   float e, float f, float g, float h) {
    union { uint32_t u[4]; bf16x8 v; } cv;
    cv.u[0] = cvt_pk_bf16(a, b);
    cv.u[1] = cvt_pk_bf16(c, d);
    cv.u[2] = cvt_pk_bf16(e, f);
    cv.u[3] = cvt_pk_bf16(g, h);
    return cv.v;
}

// ---------------------------------------------------------------------------
// MFMA sparse conv. One wave per 16-pair chunk. blockIdx.y = kernel offset k.
// A = gathered x rows [16x64] (registers, no LDS), B = w_k [64x64] (registers,
// loaded once per wave), C scattered with native f32 atomics.
// Fragment convention (16x16x32 bf16):
//   A: lane l holds A[l&15][(l>>4)*8 + j]      (k-permutation cancels A vs B)
//   B: lane l holds B[(l>>4)*8 + j][l&15]
//   D: lane l, reg j -> row=(l>>4)*4+j, col=l&15   (HW-verified mapping)
// ---------------------------------------------------------------------------
__global__ __launch_bounds__(256) void conv_mfma(
    const float* __restrict__ x, const float* __restrict__ w,
    const int* __restrict__ kin, const int* __restrict__ kout,
    float* __restrict__ y)
{
    const int lane = threadIdx.x & 63;
    const int wid  = threadIdx.x >> 6;
    const int k    = blockIdx.y;
    const int row  = lane & 15;   // A-row / D-col
    const int kg   = lane >> 4;   // k-group (8 k's each)

    const float* wk = w + (size_t)k * (INC * OUTC);

    // --- B fragments: bfrag[n][kk] covers cols n*16..n*16+15, k kk*32..+31 ---
    bf16x8 bfrag[4][2];
    #pragma unroll
    for (int n = 0; n < 4; ++n) {
        #pragma unroll
        for (int kk = 0; kk < 2; ++kk) {
            const int kbase = kk * 32 + kg * 8;
            const float* bp = wk + (size_t)kbase * OUTC + n * 16 + row;
            bfrag[n][kk] = pack_frag(bp[0*OUTC], bp[1*OUTC], bp[2*OUTC], bp[3*OUTC],
                                     bp[4*OUTC], bp[5*OUTC], bp[6*OUTC], bp[7*OUTC]);
        }
    }

    const int* kin_k  = kin  + (size_t)k * N_PAIRS;
    const int* kout_k = kout + (size_t)k * N_PAIRS;

    const int NCHUNK = N_PAIRS / 16;           // 6250
    const int nwaves = gridDim.x * 4;

    for (int ch = blockIdx.x * 4 + wid; ch < NCHUNK; ch += nwaves) {
        const int e0 = ch * 16;

        // gather indices
        const int in_idx = kin_k[e0 + row];                         // row of A I feed
        const int4 oi = *(const int4*)(kout_k + e0 + kg * 4);       // my 4 D-rows

        // --- A fragments: 8 consecutive floats per lane per k-half ---
        const float* xr = x + (size_t)in_idx * INC + kg * 8;
        bf16x8 afrag[2];
        #pragma unroll
        for (int kk = 0; kk < 2; ++kk) {
            const f32x4 a0 = *(const f32x4*)(xr + kk * 32);
            const f32x4 a1 = *(const f32x4*)(xr + kk * 32 + 4);
            afrag[kk] = pack_frag(a0.x, a0.y, a0.z, a0.w, a1.x, a1.y, a1.z, a1.w);
        }

        // --- MFMA: 4 N-tiles x 2 K-halves ---
        f32x4 acc[4] = {{0,0,0,0},{0,0,0,0},{0,0,0,0},{0,0,0,0}};
        #pragma unroll
        for (int n = 0; n < 4; ++n) {
            acc[n] = __builtin_amdgcn_mfma_f32_16x16x32_bf16(afrag[0], bfrag[n][0], acc[n], 0, 0, 0);
            acc[n] = __builtin_amdgcn_mfma_f32_16x16x32_bf16(afrag[1], bfrag[n][1], acc[n], 0, 0, 0);
        }

        // --- scatter: D row = kg*4+j, col = n*16 + row ---
        const int orow[4] = {oi.x, oi.y, oi.z, oi.w};
        #pragma unroll
        for (int j = 0; j < 4; ++j) {
            float* base = y + (size_t)orow[j] * OUTC + row;
            unsafeAtomicAdd(base + 0,  acc[0][j]);
            unsafeAtomicAdd(base + 16, acc[1][j]);
            unsafeAtomicAdd(base + 32, acc[2][j]);
            unsafeAtomicAdd(base + 48, acc[3][j]);
        }
    }
}

// ---------------------------------------------------------------------------
// BN stats: per-channel sum and sum-of-squares over all N_VOX rows.
// ---------------------------------------------------------------------------
__global__ __launch_bounds__(256) void bn_reduce(
    const float* __restrict__ y, float* __restrict__ stats)
{
    __shared__ float s_sum[256];
    __shared__ float s_sq[256];

    const int c = threadIdx.x & 63;
    const int row0 = (blockIdx.x * blockDim.x + threadIdx.x) >> 6;
    const int rstride = (gridDim.x * blockDim.x) >> 6;

    float s = 0.f, ss = 0.f;
    for (int r = row0; r < N_VOX; r += rstride) {
        const float v = y[(size_t)r * OUTC + c];
        s += v;
        ss += v * v;
    }
    s_sum[threadIdx.x] = s;
    s_sq[threadIdx.x]  = ss;
    __syncthreads();

    if (threadIdx.x < 64) {
        const float ts  = (s_sum[c] + s_sum[64 + c]) + (s_sum[128 + c] + s_sum[192 + c]);
        const float tss = (s_sq[c]  + s_sq[64 + c])  + (s_sq[128 + c]  + s_sq[192 + c]);
        atomicAdd(&stats[c], ts);
        atomicAdd(&stats[64 + c], tss);
    }
}

__global__ void bn_finalize(
    const float* __restrict__ stats, const float* __restrict__ gamma,
    const float* __restrict__ beta, float* __restrict__ coef)
{
    const int c = threadIdx.x;
    if (c < 64) {
        const float inv_n = 1.0f / (float)N_VOX;
        const float mean  = stats[c] * inv_n;
        const float var   = stats[64 + c] * inv_n - mean * mean;
        const float scale = gamma[c] * rsqrtf(var + BN_EPS);
        coef[c]      = scale;
        coef[64 + c] = beta[c] - mean * scale;
    }
}

__global__ __launch_bounds__(256) void bn_apply(
    float* __restrict__ y, const float* __restrict__ coef)
{
    const size_t total4 = (size_t)N_VOX * OUTC / 4;
    size_t i = (size_t)blockIdx.x * blockDim.x + threadIdx.x;
    const size_t stride = (size_t)gridDim.x * blockDim.x;

    const int c0 = (int)((i * 4) & 63);
    const float sc0 = coef[c0 + 0], sh0 = coef[64 + c0 + 0];
    const float sc1 = coef[c0 + 1], sh1 = coef[64 + c0 + 1];
    const float sc2 = coef[c0 + 2], sh2 = coef[64 + c0 + 2];
    const float sc3 = coef[c0 + 3], sh3 = coef[64 + c0 + 3];

    float4* y4 = (float4*)y;
    for (; i < total4; i += stride) {
        float4 v = y4[i];
        v.x = fmaxf(0.f, fmaf(v.x, sc0, sh0));
        v.y = fmaxf(0.f, fmaf(v.y, sc1, sh1));
        v.z = fmaxf(0.f, fmaf(v.z, sc2, sh2));
        v.w = fmaxf(0.f, fmaf(v.w, sc3, sh3));
        y4[i] = v;
    }
}

extern "C" void kernel_launch(void* const* d_in, const int* in_sizes, int n_in,
                              void* d_out, int out_size, void* d_ws, size_t ws_size,
                              hipStream_t stream)
{
    const float* x     = (const float*)d_in[0];
    const float* w     = (const float*)d_in[1];
    const float* gamma = (const float*)d_in[2];
    const float* beta  = (const float*)d_in[3];
    const int*   kin   = (const int*)d_in[4];
    const int*   kout  = (const int*)d_in[5];

    float* y     = (float*)d_out;
    float* stats = (float*)d_ws;
    float* coef  = stats + 128;

    hipMemsetAsync(y, 0, (size_t)N_VOX * OUTC * sizeof(float), stream);
    hipMemsetAsync(stats, 0, 128 * sizeof(float), stream);

    conv_mfma<<<dim3(64, KK), 256, 0, stream>>>(x, w, kin, kout, y);
    bn_reduce<<<512, 256, 0, stream>>>(y, stats);
    bn_finalize<<<1, 64, 0, stream>>>(stats, gamma, beta, coef);
    bn_apply<<<2048, 256, 0, stream>>>(y, coef);
}

// Round 3
// 606.842 us; speedup vs baseline: 1.2153x; 1.0172x over previous
//
#include <hip/hip_runtime.h>
#include <hip/hip_fp16.h>
#include <cstdint>

#define N_VOX   200000
#define N_PAIRS 100000
#define KK      27
#define INC     64
#define OUTC    64
#define BN_EPS  1e-5f

typedef __attribute__((ext_vector_type(8))) short bf16x8;
typedef __attribute__((ext_vector_type(4))) float f32x4;

__device__ inline uint32_t cvt_pk_bf16(float lo, float hi) {
    uint32_t r;
    asm("v_cvt_pk_bf16_f32 %0, %1, %2" : "=v"(r) : "v"(lo), "v"(hi));
    return r;
}

__device__ inline bf16x8 pack_frag(float a, float b, float c, float d,
                                   float e, float f, float g, float h) {
    union { uint32_t u[4]; bf16x8 v; } cv;
    cv.u[0] = cvt_pk_bf16(a, b);
    cv.u[1] = cvt_pk_bf16(c, d);
    cv.u[2] = cvt_pk_bf16(e, f);
    cv.u[3] = cvt_pk_bf16(g, h);
    return cv.v;
}

// ---------------------------------------------------------------------------
// Shared MFMA body: computes acc[4] (n-tiles) for one 16-pair chunk.
// Fragment convention (16x16x32 bf16):
//   A: lane l holds A[l&15][(l>>4)*8 + j]   (k-permutation cancels A vs B)
//   B: lane l holds B[(l>>4)*8 + j][l&15]
//   D: lane l, reg j -> row=(l>>4)*4+j, col=l&15   (HW-verified mapping)
// ---------------------------------------------------------------------------

// ============================ fp16-accum path ==============================
__global__ __launch_bounds__(256) void conv_mfma16(
    const float* __restrict__ x, const float* __restrict__ w,
    const int* __restrict__ kin, const int* __restrict__ kout,
    __half2* __restrict__ y2)
{
    const int lane = threadIdx.x & 63;
    const int wid  = threadIdx.x >> 6;
    const int k    = blockIdx.y;
    const int row  = lane & 15;
    const int kg   = lane >> 4;

    const float* wk = w + (size_t)k * (INC * OUTC);

    bf16x8 bfrag[4][2];
    #pragma unroll
    for (int n = 0; n < 4; ++n) {
        #pragma unroll
        for (int kk = 0; kk < 2; ++kk) {
            const int kbase = kk * 32 + kg * 8;
            const float* bp = wk + (size_t)kbase * OUTC + n * 16 + row;
            bfrag[n][kk] = pack_frag(bp[0*OUTC], bp[1*OUTC], bp[2*OUTC], bp[3*OUTC],
                                     bp[4*OUTC], bp[5*OUTC], bp[6*OUTC], bp[7*OUTC]);
        }
    }

    const int* kin_k  = kin  + (size_t)k * N_PAIRS;
    const int* kout_k = kout + (size_t)k * N_PAIRS;

    const int NCHUNK = N_PAIRS / 16;
    const int nwaves = gridDim.x * 4;

    for (int ch = blockIdx.x * 4 + wid; ch < NCHUNK; ch += nwaves) {
        const int e0 = ch * 16;

        const int in_idx = kin_k[e0 + row];
        const int4 oi = *(const int4*)(kout_k + e0 + kg * 4);

        const float* xr = x + (size_t)in_idx * INC + kg * 8;
        bf16x8 afrag[2];
        #pragma unroll
        for (int kk = 0; kk < 2; ++kk) {
            const f32x4 a0 = *(const f32x4*)(xr + kk * 32);
            const f32x4 a1 = *(const f32x4*)(xr + kk * 32 + 4);
            afrag[kk] = pack_frag(a0.x, a0.y, a0.z, a0.w, a1.x, a1.y, a1.z, a1.w);
        }

        f32x4 acc[4] = {{0,0,0,0},{0,0,0,0},{0,0,0,0},{0,0,0,0}};
        #pragma unroll
        for (int n = 0; n < 4; ++n) {
            acc[n] = __builtin_amdgcn_mfma_f32_16x16x32_bf16(afrag[0], bfrag[n][0], acc[n], 0, 0, 0);
            acc[n] = __builtin_amdgcn_mfma_f32_16x16x32_bf16(afrag[1], bfrag[n][1], acc[n], 0, 0, 0);
        }

        // Scatter: pack channel pairs (2c,2c+1) via lane-pair exchange, then
        // one packed-f16 atomic per pair from even lanes (32 lane-ops/instr).
        const int orow[4] = {oi.x, oi.y, oi.z, oi.w};
        #pragma unroll
        for (int j = 0; j < 4; ++j) {
            __half2* rbase = y2 + (size_t)orow[j] * (OUTC/2) + (row >> 1);
            #pragma unroll
            for (int n = 0; n < 4; ++n) {
                const float v = acc[n][j];
                const float p = __shfl_xor(v, 1);
                if (!(lane & 1)) {
                    __half2 h = __floats2half2_rn(v, p);
                    uint32_t u; __builtin_memcpy(&u, &h, 4);
                    __half2* addr = rbase + n * 8;
                    asm volatile("global_atomic_pk_add_f16 %0, %1, off"
                                 : : "v"(addr), "v"(u) : "memory");
                }
            }
        }
    }
}

__global__ __launch_bounds__(256) void bn_reduce16(
    const __half2* __restrict__ y2, float* __restrict__ stats)
{
    __shared__ float s0a[256], s1a[256], q0a[256], q1a[256];

    const int c2 = threadIdx.x & 31;                       // channel-pair index
    const int row0 = (blockIdx.x * blockDim.x + threadIdx.x) >> 5;
    const int rstride = (gridDim.x * blockDim.x) >> 5;

    float s0 = 0.f, s1 = 0.f, q0 = 0.f, q1 = 0.f;
    for (int r = row0; r < N_VOX; r += rstride) {
        const float2 v = __half22float2(y2[(size_t)r * 32 + c2]);
        s0 += v.x; q0 += v.x * v.x;
        s1 += v.y; q1 += v.y * v.y;
    }
    s0a[threadIdx.x] = s0; s1a[threadIdx.x] = s1;
    q0a[threadIdx.x] = q0; q1a[threadIdx.x] = q1;
    __syncthreads();

    if (threadIdx.x < 64) {
        const int c = threadIdx.x, p = c >> 1, b = c & 1;
        float ts = 0.f, tq = 0.f;
        #pragma unroll
        for (int g = 0; g < 8; ++g) {
            ts += b ? s1a[g * 32 + p] : s0a[g * 32 + p];
            tq += b ? q1a[g * 32 + p] : q0a[g * 32 + p];
        }
        atomicAdd(&stats[c], ts);
        atomicAdd(&stats[64 + c], tq);
    }
}

__global__ __launch_bounds__(256) void bn_apply16(
    const __half2* __restrict__ y2, const float* __restrict__ coef,
    float2* __restrict__ out2)
{
    const size_t total2 = (size_t)N_VOX * 32;              // half2 elements
    size_t i = (size_t)blockIdx.x * blockDim.x + threadIdx.x;
    const size_t stride = (size_t)gridDim.x * blockDim.x;  // multiple of 32

    const int c2 = (int)(i & 31);
    const float sc0 = coef[2*c2], sh0 = coef[64 + 2*c2];
    const float sc1 = coef[2*c2 + 1], sh1 = coef[64 + 2*c2 + 1];

    for (; i < total2; i += stride) {
        const float2 v = __half22float2(y2[i]);
        float2 o;
        o.x = fmaxf(0.f, fmaf(v.x, sc0, sh0));
        o.y = fmaxf(0.f, fmaf(v.y, sc1, sh1));
        out2[i] = o;
    }
}

// ============================ f32 fallback path ============================
__global__ __launch_bounds__(256) void conv_mfma(
    const float* __restrict__ x, const float* __restrict__ w,
    const int* __restrict__ kin, const int* __restrict__ kout,
    float* __restrict__ y)
{
    const int lane = threadIdx.x & 63;
    const int wid  = threadIdx.x >> 6;
    const int k    = blockIdx.y;
    const int row  = lane & 15;
    const int kg   = lane >> 4;

    const float* wk = w + (size_t)k * (INC * OUTC);

    bf16x8 bfrag[4][2];
    #pragma unroll
    for (int n = 0; n < 4; ++n) {
        #pragma unroll
        for (int kk = 0; kk < 2; ++kk) {
            const int kbase = kk * 32 + kg * 8;
            const float* bp = wk + (size_t)kbase * OUTC + n * 16 + row;
            bfrag[n][kk] = pack_frag(bp[0*OUTC], bp[1*OUTC], bp[2*OUTC], bp[3*OUTC],
                                     bp[4*OUTC], bp[5*OUTC], bp[6*OUTC], bp[7*OUTC]);
        }
    }

    const int* kin_k  = kin  + (size_t)k * N_PAIRS;
    const int* kout_k = kout + (size_t)k * N_PAIRS;

    const int NCHUNK = N_PAIRS / 16;
    const int nwaves = gridDim.x * 4;

    for (int ch = blockIdx.x * 4 + wid; ch < NCHUNK; ch += nwaves) {
        const int e0 = ch * 16;
        const int in_idx = kin_k[e0 + row];
        const int4 oi = *(const int4*)(kout_k + e0 + kg * 4);

        const float* xr = x + (size_t)in_idx * INC + kg * 8;
        bf16x8 afrag[2];
        #pragma unroll
        for (int kk = 0; kk < 2; ++kk) {
            const f32x4 a0 = *(const f32x4*)(xr + kk * 32);
            const f32x4 a1 = *(const f32x4*)(xr + kk * 32 + 4);
            afrag[kk] = pack_frag(a0.x, a0.y, a0.z, a0.w, a1.x, a1.y, a1.z, a1.w);
        }

        f32x4 acc[4] = {{0,0,0,0},{0,0,0,0},{0,0,0,0},{0,0,0,0}};
        #pragma unroll
        for (int n = 0; n < 4; ++n) {
            acc[n] = __builtin_amdgcn_mfma_f32_16x16x32_bf16(afrag[0], bfrag[n][0], acc[n], 0, 0, 0);
            acc[n] = __builtin_amdgcn_mfma_f32_16x16x32_bf16(afrag[1], bfrag[n][1], acc[n], 0, 0, 0);
        }

        const int orow[4] = {oi.x, oi.y, oi.z, oi.w};
        #pragma unroll
        for (int j = 0; j < 4; ++j) {
            float* base = y + (size_t)orow[j] * OUTC + row;
            unsafeAtomicAdd(base + 0,  acc[0][j]);
            unsafeAtomicAdd(base + 16, acc[1][j]);
            unsafeAtomicAdd(base + 32, acc[2][j]);
            unsafeAtomicAdd(base + 48, acc[3][j]);
        }
    }
}

__global__ __launch_bounds__(256) void bn_reduce(
    const float* __restrict__ y, float* __restrict__ stats)
{
    __shared__ float s_sum[256];
    __shared__ float s_sq[256];

    const int c = threadIdx.x & 63;
    const int row0 = (blockIdx.x * blockDim.x + threadIdx.x) >> 6;
    const int rstride = (gridDim.x * blockDim.x) >> 6;

    float s = 0.f, ss = 0.f;
    for (int r = row0; r < N_VOX; r += rstride) {
        const float v = y[(size_t)r * OUTC + c];
        s += v;
        ss += v * v;
    }
    s_sum[threadIdx.x] = s;
    s_sq[threadIdx.x]  = ss;
    __syncthreads();

    if (threadIdx.x < 64) {
        const float ts  = (s_sum[c] + s_sum[64 + c]) + (s_sum[128 + c] + s_sum[192 + c]);
        const float tss = (s_sq[c]  + s_sq[64 + c])  + (s_sq[128 + c]  + s_sq[192 + c]);
        atomicAdd(&stats[c], ts);
        atomicAdd(&stats[64 + c], tss);
    }
}

__global__ void bn_finalize(
    const float* __restrict__ stats, const float* __restrict__ gamma,
    const float* __restrict__ beta, float* __restrict__ coef)
{
    const int c = threadIdx.x;
    if (c < 64) {
        const float inv_n = 1.0f / (float)N_VOX;
        const float mean  = stats[c] * inv_n;
        const float var   = stats[64 + c] * inv_n - mean * mean;
        const float scale = gamma[c] * rsqrtf(var + BN_EPS);
        coef[c]      = scale;
        coef[64 + c] = beta[c] - mean * scale;
    }
}

__global__ __launch_bounds__(256) void bn_apply(
    float* __restrict__ y, const float* __restrict__ coef)
{
    const size_t total4 = (size_t)N_VOX * OUTC / 4;
    size_t i = (size_t)blockIdx.x * blockDim.x + threadIdx.x;
    const size_t stride = (size_t)gridDim.x * blockDim.x;

    const int c0 = (int)((i * 4) & 63);
    const float sc0 = coef[c0 + 0], sh0 = coef[64 + c0 + 0];
    const float sc1 = coef[c0 + 1], sh1 = coef[64 + c0 + 1];
    const float sc2 = coef[c0 + 2], sh2 = coef[64 + c0 + 2];
    const float sc3 = coef[c0 + 3], sh3 = coef[64 + c0 + 3];

    float4* y4 = (float4*)y;
    for (; i < total4; i += stride) {
        float4 v = y4[i];
        v.x = fmaxf(0.f, fmaf(v.x, sc0, sh0));
        v.y = fmaxf(0.f, fmaf(v.y, sc1, sh1));
        v.z = fmaxf(0.f, fmaf(v.z, sc2, sh2));
        v.w = fmaxf(0.f, fmaf(v.w, sc3, sh3));
        y4[i] = v;
    }
}

extern "C" void kernel_launch(void* const* d_in, const int* in_sizes, int n_in,
                              void* d_out, int out_size, void* d_ws, size_t ws_size,
                              hipStream_t stream)
{
    const float* x     = (const float*)d_in[0];
    const float* w     = (const float*)d_in[1];
    const float* gamma = (const float*)d_in[2];
    const float* beta  = (const float*)d_in[3];
    const int*   kin   = (const int*)d_in[4];
    const int*   kout  = (const int*)d_in[5];

    const size_t y16_bytes = (size_t)N_VOX * OUTC * sizeof(__half);   // 25.6 MB
    const size_t need = y16_bytes + 1024;

    if (ws_size >= need) {
        // fp16 packed-atomic path
        __half2* y2   = (__half2*)d_ws;
        float* stats  = (float*)((char*)d_ws + y16_bytes);
        float* coef   = stats + 128;

        hipMemsetAsync(y2, 0, y16_bytes, stream);
        hipMemsetAsync(stats, 0, 128 * sizeof(float), stream);

        conv_mfma16<<<dim3(64, KK), 256, 0, stream>>>(x, w, kin, kout, y2);
        bn_reduce16<<<512, 256, 0, stream>>>(y2, stats);
        bn_finalize<<<1, 64, 0, stream>>>(stats, gamma, beta, coef);
        bn_apply16<<<2048, 256, 0, stream>>>(y2, coef, (float2*)d_out);
    } else {
        // f32 fallback
        float* y     = (float*)d_out;
        float* stats = (float*)d_ws;
        float* coef  = stats + 128;

        hipMemsetAsync(y, 0, (size_t)N_VOX * OUTC * sizeof(float), stream);
        hipMemsetAsync(stats, 0, 128 * sizeof(float), stream);

        conv_mfma<<<dim3(64, KK), 256, 0, stream>>>(x, w, kin, kout, y);
        bn_reduce<<<512, 256, 0, stream>>>(y, stats);
        bn_finalize<<<1, 64, 0, stream>>>(stats, gamma, beta, coef);
        bn_apply<<<2048, 256, 0, stream>>>(y, coef);
    }
}